// Round 1
// baseline (1549.431 us; speedup 1.0000x reference)
//
#include <hip/hip_runtime.h>
#include <math.h>

#define B_ 2
#define S_ 2048
#define C_ 1024
#define H_ 16
#define D_ 64
#define INV_SQRT_D 0.125f

#define LD4(p) (*reinterpret_cast<const float4*>(p))
#define ST4(p) (*reinterpret_cast<float4*>(p))

// ---------------------------------------------------------------------------
// QKV projection: out[m,n] = sum_k x[m,k] * W[n,k] + b[n], written to
// (B,H,S,D) layout. 128x128 tile, BK=16, 256 threads, 8x8 per thread.
// blockIdx.z selects which of {Wq,Wk,Wv}.
// ---------------------------------------------------------------------------
__global__ __launch_bounds__(256)
void qkv_gemm(const float* __restrict__ x,
              const float* __restrict__ Wq, const float* __restrict__ bq,
              const float* __restrict__ Wk, const float* __restrict__ bk,
              const float* __restrict__ Wv, const float* __restrict__ bv,
              float* __restrict__ qo, float* __restrict__ ko, float* __restrict__ vo)
{
    const int which = blockIdx.z;
    const float* W    = (which == 0) ? Wq : (which == 1) ? Wk : Wv;
    const float* bias = (which == 0) ? bq : (which == 1) ? bk : bv;
    float* out        = (which == 0) ? qo : (which == 1) ? ko : vo;

    const int mb = blockIdx.x * 128;
    const int nb = blockIdx.y * 128;
    const int tid = threadIdx.x;
    const int ty = tid >> 4;         // 0..15
    const int tx = tid & 15;         // 0..15

    __shared__ __align__(16) float Xs[16][132];   // [k][m] transposed
    __shared__ __align__(16) float Ws_[16][132];  // [k][n] transposed

    float acc[8][8];
#pragma unroll
    for (int i = 0; i < 8; ++i)
#pragma unroll
        for (int j = 0; j < 8; ++j) acc[i][j] = 0.f;

    const int lr = tid >> 2;          // 0..63
    const int lk = (tid & 3) << 2;    // 0,4,8,12

    for (int k0 = 0; k0 < C_; k0 += 16) {
        float4 xv0 = LD4(&x[(size_t)(mb + lr) * C_ + k0 + lk]);
        float4 xv1 = LD4(&x[(size_t)(mb + 64 + lr) * C_ + k0 + lk]);
        float4 wv0 = LD4(&W[(size_t)(nb + lr) * C_ + k0 + lk]);
        float4 wv1 = LD4(&W[(size_t)(nb + 64 + lr) * C_ + k0 + lk]);
        __syncthreads();   // previous iteration's readers done
        Xs[lk + 0][lr] = xv0.x; Xs[lk + 1][lr] = xv0.y; Xs[lk + 2][lr] = xv0.z; Xs[lk + 3][lr] = xv0.w;
        Xs[lk + 0][64 + lr] = xv1.x; Xs[lk + 1][64 + lr] = xv1.y; Xs[lk + 2][64 + lr] = xv1.z; Xs[lk + 3][64 + lr] = xv1.w;
        Ws_[lk + 0][lr] = wv0.x; Ws_[lk + 1][lr] = wv0.y; Ws_[lk + 2][lr] = wv0.z; Ws_[lk + 3][lr] = wv0.w;
        Ws_[lk + 0][64 + lr] = wv1.x; Ws_[lk + 1][64 + lr] = wv1.y; Ws_[lk + 2][64 + lr] = wv1.z; Ws_[lk + 3][64 + lr] = wv1.w;
        __syncthreads();
#pragma unroll
        for (int kk = 0; kk < 16; ++kk) {
            float a[8], b[8];
            float4 t0 = LD4(&Xs[kk][ty * 4]);       a[0] = t0.x; a[1] = t0.y; a[2] = t0.z; a[3] = t0.w;
            float4 t1 = LD4(&Xs[kk][64 + ty * 4]);  a[4] = t1.x; a[5] = t1.y; a[6] = t1.z; a[7] = t1.w;
            float4 t2 = LD4(&Ws_[kk][tx * 4]);      b[0] = t2.x; b[1] = t2.y; b[2] = t2.z; b[3] = t2.w;
            float4 t3 = LD4(&Ws_[kk][64 + tx * 4]); b[4] = t3.x; b[5] = t3.y; b[6] = t3.z; b[7] = t3.w;
#pragma unroll
            for (int i = 0; i < 8; ++i)
#pragma unroll
                for (int j = 0; j < 8; ++j)
                    acc[i][j] = fmaf(a[i], b[j], acc[i][j]);
        }
    }

    float bloc[8];
    {
        float4 bb0 = LD4(&bias[nb + tx * 4]);
        float4 bb1 = LD4(&bias[nb + 64 + tx * 4]);
        bloc[0] = bb0.x; bloc[1] = bb0.y; bloc[2] = bb0.z; bloc[3] = bb0.w;
        bloc[4] = bb1.x; bloc[5] = bb1.y; bloc[6] = bb1.z; bloc[7] = bb1.w;
    }

#pragma unroll
    for (int i = 0; i < 8; ++i) {
        int r = (i < 4) ? (ty * 4 + i) : (64 + ty * 4 + (i - 4));
        int m = mb + r;
        int bb = m >> 11;          // m / S_
        int s  = m & (S_ - 1);
#pragma unroll
        for (int jh = 0; jh < 2; ++jh) {
            int n0 = nb + jh * 64 + tx * 4;
            int h  = n0 >> 6;
            int d  = n0 & 63;
            float4 v;
            v.x = acc[i][jh * 4 + 0] + bloc[jh * 4 + 0];
            v.y = acc[i][jh * 4 + 1] + bloc[jh * 4 + 1];
            v.z = acc[i][jh * 4 + 2] + bloc[jh * 4 + 2];
            v.w = acc[i][jh * 4 + 3] + bloc[jh * 4 + 3];
            ST4(&out[(((size_t)bb * H_ + h) * S_ + s) * D_ + d]) = v;
        }
    }
}

// ---------------------------------------------------------------------------
// Flash attention with relative-position bias.
// grid = (S/64, B*H), block = 256.  Q tile 64 rows; K/V tiles of 64.
// Per thread: 4x4 score tile (rows ty*4.., cols tx*4..), 4x4 output tile
// (rows ty*4.., dims tx*4..).
// ---------------------------------------------------------------------------
__global__ __launch_bounds__(256)
void attn_kernel(const float* __restrict__ q, const float* __restrict__ k,
                 const float* __restrict__ v, const int* __restrict__ mask,
                 const float* __restrict__ rel, float* __restrict__ ctx)
{
    const int qb = blockIdx.x * 64;
    const int bh = blockIdx.y;
    const int b = bh >> 4, h = bh & 15;
    const float* qh = q + (size_t)bh * S_ * D_;
    const float* kh = k + (size_t)bh * S_ * D_;
    const float* vh = v + (size_t)bh * S_ * D_;

    const int tid = threadIdx.x;
    const int ty = tid >> 4, tx = tid & 15;
    const int pr = tid >> 4;           // staging row within pass
    const int pc = (tid & 15) << 2;    // staging col*4

    __shared__ __align__(16) float Qs[64][68];   // [d][row]  (transposed)
    __shared__ __align__(16) float Ks[64][68];   // [d][col]  (transposed)
    __shared__ __align__(16) float Vs[64][68];   // [row][d]
    __shared__ __align__(16) float Ps[64][68];   // [qrow][j]
    __shared__ float Prj[64][12];                // rel projections [row][0..8]

    // stage Q (transposed)
#pragma unroll
    for (int p = 0; p < 4; ++p) {
        int r = p * 16 + pr;
        float4 t = LD4(&qh[(size_t)(qb + r) * D_ + pc]);
        Qs[pc + 0][r] = t.x; Qs[pc + 1][r] = t.y; Qs[pc + 2][r] = t.z; Qs[pc + 3][r] = t.w;
    }
    __syncthreads();

    // rel-position projections: proj[row][r] = inv * sum_d Q[row][d]*rel[r][d]
    for (int e = tid; e < 64 * 9; e += 256) {
        int row = e / 9, rr = e - row * 9;
        float s0 = 0.f;
        for (int d0 = 0; d0 < 64; ++d0) s0 += Qs[d0][row] * rel[rr * D_ + d0];
        Prj[row][rr] = s0 * INV_SQRT_D;
    }

    float o[4][4];
    float mrun[4], lrun[4];
#pragma unroll
    for (int i = 0; i < 4; ++i) {
        mrun[i] = -INFINITY; lrun[i] = 0.f;
#pragma unroll
        for (int j = 0; j < 4; ++j) o[i][j] = 0.f;
    }

    for (int jt = 0; jt < S_ / 64; ++jt) {
        const int jb = jt * 64;
        float4 kreg[4], vreg[4];
#pragma unroll
        for (int p = 0; p < 4; ++p) {
            int r = p * 16 + pr;
            kreg[p] = LD4(&kh[(size_t)(jb + r) * D_ + pc]);
            vreg[p] = LD4(&vh[(size_t)(jb + r) * D_ + pc]);
        }
        __syncthreads();   // prior PV readers done (also orders Prj writes->reads on jt==0)
#pragma unroll
        for (int p = 0; p < 4; ++p) {
            int r = p * 16 + pr;
            Ks[pc + 0][r] = kreg[p].x; Ks[pc + 1][r] = kreg[p].y;
            Ks[pc + 2][r] = kreg[p].z; Ks[pc + 3][r] = kreg[p].w;
            ST4(&Vs[r][pc]) = vreg[p];
        }
        __syncthreads();

        // S = Q K^T
        float s[4][4];
#pragma unroll
        for (int i = 0; i < 4; ++i)
#pragma unroll
            for (int j = 0; j < 4; ++j) s[i][j] = 0.f;
        for (int kd = 0; kd < 64; ++kd) {
            float4 qa = LD4(&Qs[kd][ty * 4]);
            float4 ka = LD4(&Ks[kd][tx * 4]);
            s[0][0] = fmaf(qa.x, ka.x, s[0][0]); s[0][1] = fmaf(qa.x, ka.y, s[0][1]);
            s[0][2] = fmaf(qa.x, ka.z, s[0][2]); s[0][3] = fmaf(qa.x, ka.w, s[0][3]);
            s[1][0] = fmaf(qa.y, ka.x, s[1][0]); s[1][1] = fmaf(qa.y, ka.y, s[1][1]);
            s[1][2] = fmaf(qa.y, ka.z, s[1][2]); s[1][3] = fmaf(qa.y, ka.w, s[1][3]);
            s[2][0] = fmaf(qa.z, ka.x, s[2][0]); s[2][1] = fmaf(qa.z, ka.y, s[2][1]);
            s[2][2] = fmaf(qa.z, ka.z, s[2][2]); s[2][3] = fmaf(qa.z, ka.w, s[2][3]);
            s[3][0] = fmaf(qa.w, ka.x, s[3][0]); s[3][1] = fmaf(qa.w, ka.y, s[3][1]);
            s[3][2] = fmaf(qa.w, ka.z, s[3][2]); s[3][3] = fmaf(qa.w, ka.w, s[3][3]);
        }

        // finalize: scale, rel bias, mask
        int4 mv = *reinterpret_cast<const int4*>(&mask[b * S_ + jb + tx * 4]);
        int mk[4] = { mv.x, mv.y, mv.z, mv.w };
#pragma unroll
        for (int i = 0; i < 4; ++i) {
            int ig = qb + ty * 4 + i;
#pragma unroll
            for (int j = 0; j < 4; ++j) {
                int jg = jb + tx * 4 + j;
                int dp = jg - ig;
                dp = dp < -4 ? -4 : (dp > 4 ? 4 : dp);
                float val = s[i][j] * INV_SQRT_D + Prj[ty * 4 + i][dp + 4];
                if (mk[j] == 0) val = -1.0e9f;
                s[i][j] = val;
            }
        }

        // online softmax (row stats across the 16 tx lanes)
#pragma unroll
        for (int i = 0; i < 4; ++i) {
            float mx = fmaxf(fmaxf(s[i][0], s[i][1]), fmaxf(s[i][2], s[i][3]));
            mx = fmaxf(mx, __shfl_xor(mx, 1));
            mx = fmaxf(mx, __shfl_xor(mx, 2));
            mx = fmaxf(mx, __shfl_xor(mx, 4));
            mx = fmaxf(mx, __shfl_xor(mx, 8));
            float mnew = fmaxf(mrun[i], mx);
            float scl = expf(mrun[i] - mnew);
            float rs = 0.f;
#pragma unroll
            for (int j = 0; j < 4; ++j) {
                float pv = expf(s[i][j] - mnew);
                s[i][j] = pv; rs += pv;
            }
            rs += __shfl_xor(rs, 1); rs += __shfl_xor(rs, 2);
            rs += __shfl_xor(rs, 4); rs += __shfl_xor(rs, 8);
            lrun[i] = lrun[i] * scl + rs;
            mrun[i] = mnew;
            o[i][0] *= scl; o[i][1] *= scl; o[i][2] *= scl; o[i][3] *= scl;
            Ps[ty * 4 + i][tx * 4 + 0] = s[i][0];
            Ps[ty * 4 + i][tx * 4 + 1] = s[i][1];
            Ps[ty * 4 + i][tx * 4 + 2] = s[i][2];
            Ps[ty * 4 + i][tx * 4 + 3] = s[i][3];
        }
        __syncthreads();

        // O += P V
#pragma unroll
        for (int j0 = 0; j0 < 64; j0 += 4) {
            float4 w0 = LD4(&Vs[j0 + 0][tx * 4]);
            float4 w1 = LD4(&Vs[j0 + 1][tx * 4]);
            float4 w2 = LD4(&Vs[j0 + 2][tx * 4]);
            float4 w3 = LD4(&Vs[j0 + 3][tx * 4]);
#pragma unroll
            for (int i = 0; i < 4; ++i) {
                float4 pp = LD4(&Ps[ty * 4 + i][j0]);
                o[i][0] += pp.x * w0.x + pp.y * w1.x + pp.z * w2.x + pp.w * w3.x;
                o[i][1] += pp.x * w0.y + pp.y * w1.y + pp.z * w2.y + pp.w * w3.y;
                o[i][2] += pp.x * w0.z + pp.y * w1.z + pp.z * w2.z + pp.w * w3.z;
                o[i][3] += pp.x * w0.w + pp.y * w1.w + pp.z * w2.w + pp.w * w3.w;
            }
        }
    }

    // normalize + write ctx (B,S,C) with C index = h*64 + d
#pragma unroll
    for (int i = 0; i < 4; ++i) {
        float il = 1.0f / lrun[i];
        float4 r;
        r.x = o[i][0] * il; r.y = o[i][1] * il; r.z = o[i][2] * il; r.w = o[i][3] * il;
        ST4(&ctx[((size_t)(b * S_ + qb + ty * 4 + i)) * C_ + h * D_ + tx * 4]) = r;
    }
}

// ---------------------------------------------------------------------------
// Output projection: out[m,n] = sum_k ctx[m,k] * Wo[n,k] + bo[n]
// ---------------------------------------------------------------------------
__global__ __launch_bounds__(256)
void out_gemm(const float* __restrict__ A, const float* __restrict__ W,
              const float* __restrict__ bias, float* __restrict__ out)
{
    const int mb = blockIdx.x * 128;
    const int nb = blockIdx.y * 128;
    const int tid = threadIdx.x;
    const int ty = tid >> 4, tx = tid & 15;

    __shared__ __align__(16) float Xs[16][132];
    __shared__ __align__(16) float Ws_[16][132];

    float acc[8][8];
#pragma unroll
    for (int i = 0; i < 8; ++i)
#pragma unroll
        for (int j = 0; j < 8; ++j) acc[i][j] = 0.f;

    const int lr = tid >> 2;
    const int lk = (tid & 3) << 2;

    for (int k0 = 0; k0 < C_; k0 += 16) {
        float4 xv0 = LD4(&A[(size_t)(mb + lr) * C_ + k0 + lk]);
        float4 xv1 = LD4(&A[(size_t)(mb + 64 + lr) * C_ + k0 + lk]);
        float4 wv0 = LD4(&W[(size_t)(nb + lr) * C_ + k0 + lk]);
        float4 wv1 = LD4(&W[(size_t)(nb + 64 + lr) * C_ + k0 + lk]);
        __syncthreads();
        Xs[lk + 0][lr] = xv0.x; Xs[lk + 1][lr] = xv0.y; Xs[lk + 2][lr] = xv0.z; Xs[lk + 3][lr] = xv0.w;
        Xs[lk + 0][64 + lr] = xv1.x; Xs[lk + 1][64 + lr] = xv1.y; Xs[lk + 2][64 + lr] = xv1.z; Xs[lk + 3][64 + lr] = xv1.w;
        Ws_[lk + 0][lr] = wv0.x; Ws_[lk + 1][lr] = wv0.y; Ws_[lk + 2][lr] = wv0.z; Ws_[lk + 3][lr] = wv0.w;
        Ws_[lk + 0][64 + lr] = wv1.x; Ws_[lk + 1][64 + lr] = wv1.y; Ws_[lk + 2][64 + lr] = wv1.z; Ws_[lk + 3][64 + lr] = wv1.w;
        __syncthreads();
#pragma unroll
        for (int kk = 0; kk < 16; ++kk) {
            float a[8], b[8];
            float4 t0 = LD4(&Xs[kk][ty * 4]);       a[0] = t0.x; a[1] = t0.y; a[2] = t0.z; a[3] = t0.w;
            float4 t1 = LD4(&Xs[kk][64 + ty * 4]);  a[4] = t1.x; a[5] = t1.y; a[6] = t1.z; a[7] = t1.w;
            float4 t2 = LD4(&Ws_[kk][tx * 4]);      b[0] = t2.x; b[1] = t2.y; b[2] = t2.z; b[3] = t2.w;
            float4 t3 = LD4(&Ws_[kk][64 + tx * 4]); b[4] = t3.x; b[5] = t3.y; b[6] = t3.z; b[7] = t3.w;
#pragma unroll
            for (int i = 0; i < 8; ++i)
#pragma unroll
                for (int j = 0; j < 8; ++j)
                    acc[i][j] = fmaf(a[i], b[j], acc[i][j]);
        }
    }

    float bloc[8];
    {
        float4 bb0 = LD4(&bias[nb + tx * 4]);
        float4 bb1 = LD4(&bias[nb + 64 + tx * 4]);
        bloc[0] = bb0.x; bloc[1] = bb0.y; bloc[2] = bb0.z; bloc[3] = bb0.w;
        bloc[4] = bb1.x; bloc[5] = bb1.y; bloc[6] = bb1.z; bloc[7] = bb1.w;
    }

#pragma unroll
    for (int i = 0; i < 8; ++i) {
        int r = (i < 4) ? (ty * 4 + i) : (64 + ty * 4 + (i - 4));
        size_t m = mb + r;
#pragma unroll
        for (int jh = 0; jh < 2; ++jh) {
            int n0 = nb + jh * 64 + tx * 4;
            float4 v;
            v.x = acc[i][jh * 4 + 0] + bloc[jh * 4 + 0];
            v.y = acc[i][jh * 4 + 1] + bloc[jh * 4 + 1];
            v.z = acc[i][jh * 4 + 2] + bloc[jh * 4 + 2];
            v.w = acc[i][jh * 4 + 3] + bloc[jh * 4 + 3];
            ST4(&out[m * C_ + n0]) = v;
        }
    }
}

extern "C" void kernel_launch(void* const* d_in, const int* in_sizes, int n_in,
                              void* d_out, int out_size, void* d_ws, size_t ws_size,
                              hipStream_t stream)
{
    const float* x    = (const float*)d_in[0];
    const int*   mask = (const int*)  d_in[1];
    const float* Wq   = (const float*)d_in[2];
    const float* bq   = (const float*)d_in[3];
    const float* Wk   = (const float*)d_in[4];
    const float* bk   = (const float*)d_in[5];
    const float* Wv   = (const float*)d_in[6];
    const float* bv   = (const float*)d_in[7];
    const float* Wo   = (const float*)d_in[8];
    const float* bo   = (const float*)d_in[9];
    const float* rel  = (const float*)d_in[10];
    float* out = (float*)d_out;

    const size_t NELT = (size_t)B_ * S_ * C_;   // 4,194,304
    float* q   = (float*)d_ws;
    float* k   = q + NELT;
    float* v   = k + NELT;
    float* ctx = v + NELT;

    qkv_gemm<<<dim3(32, 8, 3), 256, 0, stream>>>(x, Wq, bq, Wk, bk, Wv, bv, q, k, v);
    attn_kernel<<<dim3(S_ / 64, B_ * H_), 256, 0, stream>>>(q, k, v, mask, rel, ctx);
    out_gemm<<<dim3(32, 8), 256, 0, stream>>>(ctx, Wo, bo, out);
}

// Round 3
// 436.869 us; speedup vs baseline: 3.5467x; 3.5467x over previous
//
#include <hip/hip_runtime.h>
#include <math.h>

#define B_ 2
#define S_ 2048
#define C_ 1024
#define H_ 16
#define D_ 64

typedef _Float16 f16;
typedef _Float16 half8 __attribute__((ext_vector_type(8)));
typedef _Float16 half4v __attribute__((ext_vector_type(4)));
typedef float floatx4 __attribute__((ext_vector_type(4)));

#define LD4F(p) (*reinterpret_cast<const float4*>(p))
#define LD16U(p) (*reinterpret_cast<const uint4*>(p))

// ---------------------------------------------------------------------------
// Convert fp32 inputs to fp16 workspace: [x (4M) | Wq | Wk | Wv | Wo (1M each)]
// ---------------------------------------------------------------------------
__global__ __launch_bounds__(256)
void convert_inputs(const float* __restrict__ x,
                    const float* __restrict__ Wq, const float* __restrict__ Wk,
                    const float* __restrict__ Wv, const float* __restrict__ Wo,
                    f16* __restrict__ dst)
{
    const size_t XN = (size_t)B_ * S_ * C_;        // 4,194,304
    const size_t WN = (size_t)C_ * C_;             // 1,048,576
    size_t i = (size_t)blockIdx.x * 256 + threadIdx.x;
    size_t e = i * 4;
    if (e >= XN + 4 * WN) return;
    const float* s; size_t o;
    if (e < XN) { s = x; o = e; }
    else {
        size_t j = e - XN;
        int w = (int)(j >> 20);
        s = (w == 0) ? Wq : (w == 1) ? Wk : (w == 2) ? Wv : Wo;
        o = j & (WN - 1);
    }
    float4 val = LD4F(&s[o]);
    half4v hv;
    hv[0] = (f16)val.x; hv[1] = (f16)val.y; hv[2] = (f16)val.z; hv[3] = (f16)val.w;
    *reinterpret_cast<half4v*>(&dst[e]) = hv;
}

// ---------------------------------------------------------------------------
// QKV projection with MFMA fp16: out = x @ W^T + b, written fp16 (B,H,S,D).
// 128x128 tile, BK=32, 256 threads = 4 waves, each wave 64x64 (4x4 frags).
// LDS rows padded to 40 halves (80B) -> frag reads spread over 8 16B slots.
// ---------------------------------------------------------------------------
__global__ __launch_bounds__(256)
void qkv_gemm_h(const f16* __restrict__ xh, const f16* __restrict__ Wbase,
                const float* __restrict__ bq, const float* __restrict__ bk,
                const float* __restrict__ bv,
                f16* __restrict__ qo, f16* __restrict__ ko, f16* __restrict__ vo)
{
    const int which = blockIdx.z;
    const f16* W      = Wbase + (size_t)which * C_ * C_;
    const float* bias = (which == 0) ? bq : (which == 1) ? bk : bv;
    f16* out          = (which == 0) ? qo : (which == 1) ? ko : vo;

    const int mb = blockIdx.x * 128;
    const int nb = blockIdx.y * 128;
    const int tid = threadIdx.x;
    const int lane = tid & 63;
    const int wid = tid >> 6;
    const int wr = wid >> 1, wc = wid & 1;
    const int l15 = lane & 15, g = lane >> 4;

    __shared__ __align__(16) f16 As[128 * 40];
    __shared__ __align__(16) f16 Bs[128 * 40];

    floatx4 acc[4][4];
#pragma unroll
    for (int m = 0; m < 4; ++m)
#pragma unroll
        for (int n = 0; n < 4; ++n) acc[m][n] = (floatx4){0.f, 0.f, 0.f, 0.f};

    for (int k0 = 0; k0 < C_; k0 += 32) {
        uint4 ra[2], rb[2];
#pragma unroll
        for (int p = 0; p < 2; ++p) {
            int idx = tid + 256 * p;          // 0..511
            int row = idx >> 2, c4 = idx & 3; // 128 rows x 4 chunks of 8 halves
            ra[p] = LD16U(&xh[(size_t)(mb + row) * C_ + k0 + c4 * 8]);
            rb[p] = LD16U(&W [(size_t)(nb + row) * C_ + k0 + c4 * 8]);
        }
        __syncthreads();
#pragma unroll
        for (int p = 0; p < 2; ++p) {
            int idx = tid + 256 * p;
            int row = idx >> 2, c4 = idx & 3;
            *reinterpret_cast<uint4*>(&As[row * 40 + c4 * 8]) = ra[p];
            *reinterpret_cast<uint4*>(&Bs[row * 40 + c4 * 8]) = rb[p];
        }
        __syncthreads();

        half8 af[4];
#pragma unroll
        for (int m = 0; m < 4; ++m)
            af[m] = *reinterpret_cast<const half8*>(&As[(wr * 64 + m * 16 + l15) * 40 + g * 8]);
#pragma unroll
        for (int n = 0; n < 4; ++n) {
            half8 bf = *reinterpret_cast<const half8*>(&Bs[(wc * 64 + n * 16 + l15) * 40 + g * 8]);
#pragma unroll
            for (int m = 0; m < 4; ++m)
                acc[m][n] = __builtin_amdgcn_mfma_f32_16x16x32_f16(af[m], bf, acc[m][n], 0, 0, 0);
        }
    }

#pragma unroll
    for (int n = 0; n < 4; ++n) {
        int col = nb + wc * 64 + n * 16 + l15;
        float bb = bias[col];
        int h = col >> 6, d = col & 63;
#pragma unroll
        for (int m = 0; m < 4; ++m)
#pragma unroll
            for (int r = 0; r < 4; ++r) {
                int row = mb + wr * 64 + m * 16 + g * 4 + r;
                int b = row >> 11, s = row & (S_ - 1);
                out[(((size_t)b * H_ + h) * S_ + s) * D_ + d] = (f16)(acc[m][n][r] + bb);
            }
    }
}

// ---------------------------------------------------------------------------
// Flash attention, fp16 MFMA. grid=(S/64, B*H), 256 threads = 4 waves.
// Each wave owns 16 Q rows; KV tiles of 64. Q/A-frags in regs, K in LDS
// (144B rows, conflict-free b128), V row-major (136B rows, u16 B-operand
// reads), P via wave-private LDS repack. Softmax fp32 online.
// ---------------------------------------------------------------------------
__global__ __launch_bounds__(256)
void attn_mfma(const f16* __restrict__ q, const f16* __restrict__ k,
               const f16* __restrict__ v, const int* __restrict__ mask,
               const float* __restrict__ rel, f16* __restrict__ ctx)
{
    const int qb = blockIdx.x * 64;
    const int bh = blockIdx.y;
    const int b = bh >> 4, h = bh & 15;
    const f16* qh_ = q + (size_t)bh * S_ * D_;
    const f16* kh_ = k + (size_t)bh * S_ * D_;
    const f16* vh_ = v + (size_t)bh * S_ * D_;

    const int tid = threadIdx.x;
    const int lane = tid & 63;
    const int wid = tid >> 6;
    const int l15 = lane & 15, g = lane >> 4;

    __shared__ __align__(16) f16 Ks[64 * 72];       // [kv][d], 144B rows
    __shared__ __align__(16) f16 Vs[64 * 68];       // [kv][d], 136B rows
    __shared__ __align__(16) f16 Ps[4][16 * 72];    // per-wave P, 144B rows
    __shared__ float Prj[64][12];

    // Q fragments (rows wid*16 + l15, k = ks*32 + g*8 + j)
    const int qrow = qb + wid * 16 + l15;
    half8 aq0 = *reinterpret_cast<const half8*>(&qh_[(size_t)qrow * D_ + g * 8]);
    half8 aq1 = *reinterpret_cast<const half8*>(&qh_[(size_t)qrow * D_ + 32 + g * 8]);

    // rel projections for this wave's 16 rows
#pragma unroll
    for (int rr = 0; rr < 9; ++rr) {
        float p = 0.f;
#pragma unroll
        for (int j = 0; j < 8; ++j) {
            p += (float)aq0[j] * rel[rr * D_ + g * 8 + j];
            p += (float)aq1[j] * rel[rr * D_ + 32 + g * 8 + j];
        }
        p += __shfl_xor(p, 16);
        p += __shfl_xor(p, 32);
        if (lane < 16) Prj[wid * 16 + l15][rr] = p * 0.125f;
    }

    floatx4 o[4];
    float mrun[4], lrun[4];
#pragma unroll
    for (int n = 0; n < 4; ++n) o[n] = (floatx4){0.f, 0.f, 0.f, 0.f};
#pragma unroll
    for (int r = 0; r < 4; ++r) { mrun[r] = -INFINITY; lrun[r] = 0.f; }

    for (int jt = 0; jt < S_ / 64; ++jt) {
        const int jb = jt * 64;
        uint4 kr[2], vr[2];
#pragma unroll
        for (int p = 0; p < 2; ++p) {
            int idx = tid + 256 * p;           // 0..511
            int row = idx >> 3, c8 = idx & 7;  // 64 rows x 8 chunks
            kr[p] = LD16U(&kh_[(size_t)(jb + row) * D_ + c8 * 8]);
            vr[p] = LD16U(&vh_[(size_t)(jb + row) * D_ + c8 * 8]);
        }
        __syncthreads();   // previous tile's readers done (and Prj on jt==0)
#pragma unroll
        for (int p = 0; p < 2; ++p) {
            int idx = tid + 256 * p;
            int row = idx >> 3, c8 = idx & 7;
            *reinterpret_cast<uint4*>(&Ks[row * 72 + c8 * 8]) = kr[p];
            const uint2* vv = reinterpret_cast<const uint2*>(&vr[p]);
            *reinterpret_cast<uint2*>(&Vs[row * 68 + c8 * 8]) = vv[0];
            *reinterpret_cast<uint2*>(&Vs[row * 68 + c8 * 8 + 4]) = vv[1];
        }
        __syncthreads();

        // S = Q K^T (fp32 acc), cols n*16+l15, rows g*4+r
        floatx4 sc[4];
#pragma unroll
        for (int n = 0; n < 4; ++n) sc[n] = (floatx4){0.f, 0.f, 0.f, 0.f};
#pragma unroll
        for (int n = 0; n < 4; ++n) {
            half8 bk0 = *reinterpret_cast<const half8*>(&Ks[(n * 16 + l15) * 72 + g * 8]);
            half8 bk1 = *reinterpret_cast<const half8*>(&Ks[(n * 16 + l15) * 72 + 32 + g * 8]);
            sc[n] = __builtin_amdgcn_mfma_f32_16x16x32_f16(aq0, bk0, sc[n], 0, 0, 0);
            sc[n] = __builtin_amdgcn_mfma_f32_16x16x32_f16(aq1, bk1, sc[n], 0, 0, 0);
        }

        // scale + rel bias + mask
        float pvv[4][4];
#pragma unroll
        for (int n = 0; n < 4; ++n) {
            int jg = jb + n * 16 + l15;
            int mv = mask[b * S_ + jg];
#pragma unroll
            for (int r = 0; r < 4; ++r) {
                int ig = qb + wid * 16 + g * 4 + r;
                int dp = jg - ig;
                dp = dp < -4 ? -4 : (dp > 4 ? 4 : dp);
                float val = sc[n][r] * 0.125f + Prj[wid * 16 + g * 4 + r][dp + 4];
                pvv[n][r] = mv ? val : -1.0e9f;
            }
        }

        // online softmax per row (16-lane col groups)
#pragma unroll
        for (int r = 0; r < 4; ++r) {
            float mx = fmaxf(fmaxf(pvv[0][r], pvv[1][r]), fmaxf(pvv[2][r], pvv[3][r]));
            mx = fmaxf(mx, __shfl_xor(mx, 1));
            mx = fmaxf(mx, __shfl_xor(mx, 2));
            mx = fmaxf(mx, __shfl_xor(mx, 4));
            mx = fmaxf(mx, __shfl_xor(mx, 8));
            float mnew = fmaxf(mrun[r], mx);
            float scl = __expf(mrun[r] - mnew);
            float rs = 0.f;
#pragma unroll
            for (int n = 0; n < 4; ++n) {
                float e = __expf(pvv[n][r] - mnew);
                pvv[n][r] = e; rs += e;
            }
            rs += __shfl_xor(rs, 1); rs += __shfl_xor(rs, 2);
            rs += __shfl_xor(rs, 4); rs += __shfl_xor(rs, 8);
            lrun[r] = lrun[r] * scl + rs;
            mrun[r] = mnew;
#pragma unroll
            for (int n = 0; n < 4; ++n) o[n][r] *= scl;
        }

        // P -> wave-private LDS (fp16), then A-frags
#pragma unroll
        for (int n = 0; n < 4; ++n)
#pragma unroll
            for (int r = 0; r < 4; ++r)
                Ps[wid][(g * 4 + r) * 72 + n * 16 + l15] = (f16)pvv[n][r];

        half8 pa0 = *reinterpret_cast<const half8*>(&Ps[wid][l15 * 72 + g * 8]);
        half8 pa1 = *reinterpret_cast<const half8*>(&Ps[wid][l15 * 72 + 32 + g * 8]);

        // O += P V : B-frag true layout, u16 column reads from Vs
#pragma unroll
        for (int n = 0; n < 4; ++n) {
            half8 bv0, bv1;
            int kv0 = g * 8;
#pragma unroll
            for (int j = 0; j < 8; ++j)
                bv0[j] = Vs[(kv0 + j) * 68 + n * 16 + l15];
#pragma unroll
            for (int j = 0; j < 8; ++j)
                bv1[j] = Vs[(32 + kv0 + j) * 68 + n * 16 + l15];
            o[n] = __builtin_amdgcn_mfma_f32_16x16x32_f16(pa0, bv0, o[n], 0, 0, 0);
            o[n] = __builtin_amdgcn_mfma_f32_16x16x32_f16(pa1, bv1, o[n], 0, 0, 0);
        }
    }

    // normalize + write ctx (B,S,C) fp16
#pragma unroll
    for (int n = 0; n < 4; ++n) {
        int dcol = n * 16 + l15;
#pragma unroll
        for (int r = 0; r < 4; ++r) {
            int srow = qb + wid * 16 + g * 4 + r;
            float val = o[n][r] / lrun[r];
            ctx[((size_t)(b * S_ + srow)) * C_ + h * D_ + dcol] = (f16)val;
        }
    }
}

// ---------------------------------------------------------------------------
// Output projection: out = ctx @ Wo^T + bo, fp32 out (B,S,C).
// ---------------------------------------------------------------------------
__global__ __launch_bounds__(256)
void out_gemm_h(const f16* __restrict__ A, const f16* __restrict__ W,
                const float* __restrict__ bias, float* __restrict__ out)
{
    const int mb = blockIdx.x * 128;
    const int nb = blockIdx.y * 128;
    const int tid = threadIdx.x;
    const int lane = tid & 63;
    const int wid = tid >> 6;
    const int wr = wid >> 1, wc = wid & 1;
    const int l15 = lane & 15, g = lane >> 4;

    __shared__ __align__(16) f16 As[128 * 40];
    __shared__ __align__(16) f16 Bs[128 * 40];

    floatx4 acc[4][4];
#pragma unroll
    for (int m = 0; m < 4; ++m)
#pragma unroll
        for (int n = 0; n < 4; ++n) acc[m][n] = (floatx4){0.f, 0.f, 0.f, 0.f};

    for (int k0 = 0; k0 < C_; k0 += 32) {
        uint4 ra[2], rb[2];
#pragma unroll
        for (int p = 0; p < 2; ++p) {
            int idx = tid + 256 * p;
            int row = idx >> 2, c4 = idx & 3;
            ra[p] = LD16U(&A[(size_t)(mb + row) * C_ + k0 + c4 * 8]);
            rb[p] = LD16U(&W[(size_t)(nb + row) * C_ + k0 + c4 * 8]);
        }
        __syncthreads();
#pragma unroll
        for (int p = 0; p < 2; ++p) {
            int idx = tid + 256 * p;
            int row = idx >> 2, c4 = idx & 3;
            *reinterpret_cast<uint4*>(&As[row * 40 + c4 * 8]) = ra[p];
            *reinterpret_cast<uint4*>(&Bs[row * 40 + c4 * 8]) = rb[p];
        }
        __syncthreads();

        half8 af[4];
#pragma unroll
        for (int m = 0; m < 4; ++m)
            af[m] = *reinterpret_cast<const half8*>(&As[(wr * 64 + m * 16 + l15) * 40 + g * 8]);
#pragma unroll
        for (int n = 0; n < 4; ++n) {
            half8 bf = *reinterpret_cast<const half8*>(&Bs[(wc * 64 + n * 16 + l15) * 40 + g * 8]);
#pragma unroll
            for (int m = 0; m < 4; ++m)
                acc[m][n] = __builtin_amdgcn_mfma_f32_16x16x32_f16(af[m], bf, acc[m][n], 0, 0, 0);
        }
    }

#pragma unroll
    for (int n = 0; n < 4; ++n) {
        int col = nb + wc * 64 + n * 16 + l15;
        float bb = bias[col];
#pragma unroll
        for (int m = 0; m < 4; ++m)
#pragma unroll
            for (int r = 0; r < 4; ++r) {
                size_t row = mb + wr * 64 + m * 16 + g * 4 + r;
                out[row * C_ + col] = acc[m][n][r] + bb;
            }
    }
}

extern "C" void kernel_launch(void* const* d_in, const int* in_sizes, int n_in,
                              void* d_out, int out_size, void* d_ws, size_t ws_size,
                              hipStream_t stream)
{
    const float* x    = (const float*)d_in[0];
    const int*   mask = (const int*)  d_in[1];
    const float* Wq   = (const float*)d_in[2];
    const float* bq   = (const float*)d_in[3];
    const float* Wk   = (const float*)d_in[4];
    const float* bk   = (const float*)d_in[5];
    const float* Wv   = (const float*)d_in[6];
    const float* bv   = (const float*)d_in[7];
    const float* Wo   = (const float*)d_in[8];
    const float* bo   = (const float*)d_in[9];
    const float* rel  = (const float*)d_in[10];
    float* out = (float*)d_out;

    const size_t XN = (size_t)B_ * S_ * C_;   // 4,194,304
    const size_t WN = (size_t)C_ * C_;        // 1,048,576

    f16* wsh  = (f16*)d_ws;
    f16* xh   = wsh;                  // 4M
    f16* Wqh  = wsh + XN;             // 4 x 1M (Wq,Wk,Wv,Wo contiguous)
    f16* Woh  = Wqh + 3 * WN;
    f16* qh   = wsh + XN + 4 * WN;    // 4M
    f16* kh   = qh + XN;
    f16* vh   = kh + XN;
    f16* ctxh = vh + XN;              // total 24M halves = 48 MB

    convert_inputs<<<8192, 256, 0, stream>>>(x, Wq, Wk, Wv, Wo, wsh);
    qkv_gemm_h<<<dim3(32, 8, 3), 256, 0, stream>>>(xh, Wqh, bq, bk, bv, qh, kh, vh);
    attn_mfma<<<dim3(S_ / 64, B_ * H_), 256, 0, stream>>>(qh, kh, vh, mask, rel, ctxh);
    out_gemm_h<<<dim3(32, 8), 256, 0, stream>>>(ctxh, Woh, bo, out);
}

// Round 5
// 388.469 us; speedup vs baseline: 3.9886x; 1.1246x over previous
//
#include <hip/hip_runtime.h>

#define B_ 2
#define S_ 2048
#define C_ 1024
#define H_ 16
#define D_ 64

typedef _Float16 f16;
typedef _Float16 half8 __attribute__((ext_vector_type(8)));
typedef _Float16 half4v __attribute__((ext_vector_type(4)));
typedef float floatx4 __attribute__((ext_vector_type(4)));

#define LD4F(p) (*reinterpret_cast<const float4*>(p))
#define LD16U(p) (*reinterpret_cast<const uint4*>(p))
#define EXP2F(x) __builtin_amdgcn_exp2f(x)

// async global->LDS 16B (dest must be linear: wave-uniform base + lane*16)
__device__ __forceinline__ void gload16(const f16* g, f16* l) {
    __builtin_amdgcn_global_load_lds(
        (const __attribute__((address_space(1))) void*)g,
        (__attribute__((address_space(3))) void*)l, 16, 0, 0);
}

// ---------------------------------------------------------------------------
// Convert fp32 inputs to fp16 workspace: [x (4M) | Wq | Wk | Wv | Wo (1M each)]
// ---------------------------------------------------------------------------
__global__ __launch_bounds__(256)
void convert_inputs(const float* __restrict__ x,
                    const float* __restrict__ Wq, const float* __restrict__ Wk,
                    const float* __restrict__ Wv, const float* __restrict__ Wo,
                    f16* __restrict__ dst)
{
    const size_t XN = (size_t)B_ * S_ * C_;
    const size_t WN = (size_t)C_ * C_;
    size_t i = (size_t)blockIdx.x * 256 + threadIdx.x;
    size_t e = i * 4;
    if (e >= XN + 4 * WN) return;
    const float* s; size_t o;
    if (e < XN) { s = x; o = e; }
    else {
        size_t j = e - XN;
        int w = (int)(j >> 20);
        s = (w == 0) ? Wq : (w == 1) ? Wk : (w == 2) ? Wv : Wo;
        o = j & (WN - 1);
    }
    float4 val = LD4F(&s[o]);
    half4v hv;
    hv[0] = (f16)val.x; hv[1] = (f16)val.y; hv[2] = (f16)val.z; hv[3] = (f16)val.w;
    *reinterpret_cast<half4v*>(&dst[e]) = hv;
}

// ---------------------------------------------------------------------------
// QKV projection, m97-style: global_load_lds 16B staging, linear [128][32]
// LDS, 2-barrier K-loop, 4 waves x (64x64 via 4x4 16x16x32 frags).
// Q output is pre-scaled by 0.125*log2(e) so attention can use exp2 directly.
// ---------------------------------------------------------------------------
__global__ __launch_bounds__(256)
void qkv_gemm_h(const f16* __restrict__ xh, const f16* __restrict__ Wbase,
                const float* __restrict__ bq, const float* __restrict__ bk,
                const float* __restrict__ bv,
                f16* __restrict__ qo, f16* __restrict__ ko, f16* __restrict__ vo)
{
    const int which = blockIdx.z;
    const f16* W      = Wbase + (size_t)which * C_ * C_;
    const float* bias = (which == 0) ? bq : (which == 1) ? bk : bv;
    f16* out          = (which == 0) ? qo : (which == 1) ? ko : vo;
    const float qscale = (which == 0) ? 0.18033688f : 1.0f;   // 0.125 * log2(e)

    const int mb = blockIdx.x * 128;
    const int nb = blockIdx.y * 128;
    const int tid = threadIdx.x;
    const int lane = tid & 63;
    const int wid = tid >> 6;
    const int wr = wid >> 1, wc = wid & 1;
    const int l15 = lane & 15, g = lane >> 4;

    __shared__ __align__(16) f16 As[128 * 32];
    __shared__ __align__(16) f16 Bs[128 * 32];

    floatx4 acc[4][4];
#pragma unroll
    for (int m = 0; m < 4; ++m)
#pragma unroll
        for (int n = 0; n < 4; ++n) acc[m][n] = (floatx4){0.f, 0.f, 0.f, 0.f};

    for (int k0 = 0; k0 < C_; k0 += 32) {
        __syncthreads();   // all waves done reading previous tile
#pragma unroll
        for (int p = 0; p < 2; ++p) {
            int i2 = tid + 256 * p;            // 0..511
            int row = i2 >> 2, c4 = i2 & 3;    // 128 rows x 4 chunks of 8 halves
            gload16(&xh[(size_t)(mb + row) * C_ + k0 + c4 * 8], &As[i2 * 8]);
            gload16(&W [(size_t)(nb + row) * C_ + k0 + c4 * 8], &Bs[i2 * 8]);
        }
        __syncthreads();   // vmcnt(0) drain -> tiles resident

        half8 af[4];
#pragma unroll
        for (int m = 0; m < 4; ++m)
            af[m] = *reinterpret_cast<const half8*>(&As[(wr * 64 + m * 16 + l15) * 32 + g * 8]);
#pragma unroll
        for (int n = 0; n < 4; ++n) {
            half8 bf = *reinterpret_cast<const half8*>(&Bs[(wc * 64 + n * 16 + l15) * 32 + g * 8]);
#pragma unroll
            for (int m = 0; m < 4; ++m)
                acc[m][n] = __builtin_amdgcn_mfma_f32_16x16x32_f16(af[m], bf, acc[m][n], 0, 0, 0);
        }
    }

#pragma unroll
    for (int n = 0; n < 4; ++n) {
        int col = nb + wc * 64 + n * 16 + l15;
        float bb = bias[col];
        int h = col >> 6, d = col & 63;
#pragma unroll
        for (int m = 0; m < 4; ++m)
#pragma unroll
            for (int r = 0; r < 4; ++r) {
                int row = mb + wr * 64 + m * 16 + g * 4 + r;
                int b = row >> 11, s = row & (S_ - 1);
                out[(((size_t)b * H_ + h) * S_ + s) * D_ + d] = (f16)((acc[m][n][r] + bb) * qscale);
            }
    }
}

// ---------------------------------------------------------------------------
// Flash attention, fp16 MFMA, exp2 softmax (Q pre-scaled by 0.125*log2e).
// grid=(32,32) remapped XCD-aware: each XCD owns 4 bh x all 32 qb so K/V
// stay L2-resident. 4 waves x 16 Q-rows; KVBLK=64. K in LDS [64][72]
// (b128 frag reads), V transposed in LDS Vt[d][kv] stride 72 (b128 B-frags,
// c8-rotated scatter writes = conflict-free). Rel-bias fast path off-diagonal.
// ---------------------------------------------------------------------------
__global__ __launch_bounds__(256)
void attn_mfma(const f16* __restrict__ q, const f16* __restrict__ k,
               const f16* __restrict__ v, const int* __restrict__ mask,
               const float* __restrict__ rel, f16* __restrict__ ctx)
{
    // XCD-aware remap: flat = y*32+x; xcd = flat&7 gets bh in [xcd*4, xcd*4+4)
    const int flat = blockIdx.y * 32 + blockIdx.x;
    const int c = flat & 7, j = flat >> 3;          // j in [0,128)
    const int bh = (c << 2) | (j >> 5);             // [0,32)
    const int qb = (j & 31) * 64;

    const int b = bh >> 4, h = bh & 15;
    const f16* qh_ = q + (size_t)bh * S_ * D_;
    const f16* kh_ = k + (size_t)bh * S_ * D_;
    const f16* vh_ = v + (size_t)bh * S_ * D_;

    const int tid = threadIdx.x;
    const int lane = tid & 63;
    const int wid = tid >> 6;
    const int l15 = lane & 15, g = lane >> 4;

    __shared__ __align__(16) f16 Ks[64 * 72];       // [kv][d], 144B rows
    __shared__ __align__(16) f16 Vt[64 * 72];       // [d][kv], 144B rows
    __shared__ __align__(16) f16 Ps[4][16 * 72];    // per-wave P
    __shared__ float Prj[64][12];

    // Q fragments (pre-scaled by 0.125*log2e at qkv epilogue)
    const int qrow = qb + wid * 16 + l15;
    half8 aq0 = *reinterpret_cast<const half8*>(&qh_[(size_t)qrow * D_ + g * 8]);
    half8 aq1 = *reinterpret_cast<const half8*>(&qh_[(size_t)qrow * D_ + 32 + g * 8]);

    // rel projections for this wave's 16 rows (already carries 0.125*log2e via Q)
#pragma unroll
    for (int rr = 0; rr < 9; ++rr) {
        float p = 0.f;
#pragma unroll
        for (int jj = 0; jj < 8; ++jj) {
            p += (float)aq0[jj] * rel[rr * D_ + g * 8 + jj];
            p += (float)aq1[jj] * rel[rr * D_ + 32 + g * 8 + jj];
        }
        p += __shfl_xor(p, 16);
        p += __shfl_xor(p, 32);
        if (lane < 16) Prj[wid * 16 + l15][rr] = p;
    }

    // per-thread preload of the saturated rel values (same wave wrote them)
    float prj_lo[4], prj_hi[4];
#pragma unroll
    for (int r = 0; r < 4; ++r) {
        prj_lo[r] = Prj[wid * 16 + g * 4 + r][0];
        prj_hi[r] = Prj[wid * 16 + g * 4 + r][8];
    }

    floatx4 o[4];
    float mrun[4], lrun[4];
#pragma unroll
    for (int n = 0; n < 4; ++n) o[n] = (floatx4){0.f, 0.f, 0.f, 0.f};
#pragma unroll
    for (int r = 0; r < 4; ++r) { mrun[r] = -INFINITY; lrun[r] = 0.f; }

    for (int jt = 0; jt < S_ / 64; ++jt) {
        const int jb = jt * 64;
        uint4 kr[2], vr[2];
#pragma unroll
        for (int p = 0; p < 2; ++p) {
            int idx = tid + 256 * p;           // 0..511
            int row = idx >> 3, c8 = idx & 7;  // 64 rows x 8 chunks of 8 halves
            kr[p] = LD16U(&kh_[(size_t)(jb + row) * D_ + c8 * 8]);
            vr[p] = LD16U(&vh_[(size_t)(jb + row) * D_ + c8 * 8]);
        }
        __syncthreads();   // previous tile's readers done
#pragma unroll
        for (int p = 0; p < 2; ++p) {
            int idx = tid + 256 * p;
            int row = idx >> 3, c8 = idx & 7;
            *reinterpret_cast<uint4*>(&Ks[row * 72 + c8 * 8]) = kr[p];
            // V transposed scatter: Vt[d][kv], d = c8*8 + jj, rotated by c8
            const f16* vp = reinterpret_cast<const f16*>(&vr[p]);
#pragma unroll
            for (int jj = 0; jj < 8; ++jj) {
                int dd = (jj + c8) & 7;
                Vt[(c8 * 8 + dd) * 72 + row] = vp[dd];
            }
        }
        __syncthreads();

        // S = Q K^T (fp32 acc, log2-domain), cols n*16+l15, rows g*4+r
        floatx4 sc[4];
#pragma unroll
        for (int n = 0; n < 4; ++n) sc[n] = (floatx4){0.f, 0.f, 0.f, 0.f};
#pragma unroll
        for (int n = 0; n < 4; ++n) {
            half8 bk0 = *reinterpret_cast<const half8*>(&Ks[(n * 16 + l15) * 72 + g * 8]);
            half8 bk1 = *reinterpret_cast<const half8*>(&Ks[(n * 16 + l15) * 72 + 32 + g * 8]);
            sc[n] = __builtin_amdgcn_mfma_f32_16x16x32_f16(aq0, bk0, sc[n], 0, 0, 0);
            sc[n] = __builtin_amdgcn_mfma_f32_16x16x32_f16(aq1, bk1, sc[n], 0, 0, 0);
        }

        // rel bias + mask. Off-diagonal tiles (29/32): dp saturated.
        float pvv[4][4];
        const bool diag = (jb >= qb - 64) && (jb <= qb + 64);
        if (!diag) {
            const float* pb = (jb > qb) ? prj_hi : prj_lo;
#pragma unroll
            for (int n = 0; n < 4; ++n) {
                int mv = mask[b * S_ + jb + n * 16 + l15];
#pragma unroll
                for (int r = 0; r < 4; ++r)
                    pvv[n][r] = mv ? (sc[n][r] + pb[r]) : -1.0e9f;
            }
        } else {
#pragma unroll
            for (int n = 0; n < 4; ++n) {
                int jg = jb + n * 16 + l15;
                int mv = mask[b * S_ + jg];
#pragma unroll
                for (int r = 0; r < 4; ++r) {
                    int ig = qb + wid * 16 + g * 4 + r;
                    int dp = jg - ig;
                    dp = dp < -4 ? -4 : (dp > 4 ? 4 : dp);
                    float val = sc[n][r] + Prj[wid * 16 + g * 4 + r][dp + 4];
                    pvv[n][r] = mv ? val : -1.0e9f;
                }
            }
        }

        // online softmax per row (16-lane col groups), exp2 domain
#pragma unroll
        for (int r = 0; r < 4; ++r) {
            float mx = fmaxf(fmaxf(pvv[0][r], pvv[1][r]), fmaxf(pvv[2][r], pvv[3][r]));
            mx = fmaxf(mx, __shfl_xor(mx, 1));
            mx = fmaxf(mx, __shfl_xor(mx, 2));
            mx = fmaxf(mx, __shfl_xor(mx, 4));
            mx = fmaxf(mx, __shfl_xor(mx, 8));
            float mnew = fmaxf(mrun[r], mx);
            float scl = EXP2F(mrun[r] - mnew);
            float rs = 0.f;
#pragma unroll
            for (int n = 0; n < 4; ++n) {
                float e = EXP2F(pvv[n][r] - mnew);
                pvv[n][r] = e; rs += e;
            }
            rs += __shfl_xor(rs, 1); rs += __shfl_xor(rs, 2);
            rs += __shfl_xor(rs, 4); rs += __shfl_xor(rs, 8);
            lrun[r] = lrun[r] * scl + rs;
            mrun[r] = mnew;
#pragma unroll
            for (int n = 0; n < 4; ++n) o[n][r] *= scl;
        }

        // P -> wave-private LDS (fp16), then A-frags
#pragma unroll
        for (int n = 0; n < 4; ++n)
#pragma unroll
            for (int r = 0; r < 4; ++r)
                Ps[wid][(g * 4 + r) * 72 + n * 16 + l15] = (f16)pvv[n][r];

        half8 pa0 = *reinterpret_cast<const half8*>(&Ps[wid][l15 * 72 + g * 8]);
        half8 pa1 = *reinterpret_cast<const half8*>(&Ps[wid][l15 * 72 + 32 + g * 8]);

        // O += P V : B-frags now contiguous b128 reads from Vt
#pragma unroll
        for (int n = 0; n < 4; ++n) {
            half8 bv0 = *reinterpret_cast<const half8*>(&Vt[(n * 16 + l15) * 72 + g * 8]);
            half8 bv1 = *reinterpret_cast<const half8*>(&Vt[(n * 16 + l15) * 72 + 32 + g * 8]);
            o[n] = __builtin_amdgcn_mfma_f32_16x16x32_f16(pa0, bv0, o[n], 0, 0, 0);
            o[n] = __builtin_amdgcn_mfma_f32_16x16x32_f16(pa1, bv1, o[n], 0, 0, 0);
        }
    }

    // normalize + write ctx (B,S,C) fp16
#pragma unroll
    for (int n = 0; n < 4; ++n) {
        int dcol = n * 16 + l15;
#pragma unroll
        for (int r = 0; r < 4; ++r) {
            int srow = qb + wid * 16 + g * 4 + r;
            float val = o[n][r] / lrun[r];
            ctx[((size_t)(b * S_ + srow)) * C_ + h * D_ + dcol] = (f16)val;
        }
    }
}

// ---------------------------------------------------------------------------
// Output projection: out = ctx @ Wo^T + bo, fp32 out. Same m97 structure.
// ---------------------------------------------------------------------------
__global__ __launch_bounds__(256)
void out_gemm_h(const f16* __restrict__ A, const f16* __restrict__ W,
                const float* __restrict__ bias, float* __restrict__ out)
{
    const int mb = blockIdx.x * 128;
    const int nb = blockIdx.y * 128;
    const int tid = threadIdx.x;
    const int lane = tid & 63;
    const int wid = tid >> 6;
    const int wr = wid >> 1, wc = wid & 1;
    const int l15 = lane & 15, g = lane >> 4;

    __shared__ __align__(16) f16 As[128 * 32];
    __shared__ __align__(16) f16 Bs[128 * 32];

    floatx4 acc[4][4];
#pragma unroll
    for (int m = 0; m < 4; ++m)
#pragma unroll
        for (int n = 0; n < 4; ++n) acc[m][n] = (floatx4){0.f, 0.f, 0.f, 0.f};

    for (int k0 = 0; k0 < C_; k0 += 32) {
        __syncthreads();
#pragma unroll
        for (int p = 0; p < 2; ++p) {
            int i2 = tid + 256 * p;
            int row = i2 >> 2, c4 = i2 & 3;
            gload16(&A[(size_t)(mb + row) * C_ + k0 + c4 * 8], &As[i2 * 8]);
            gload16(&W[(size_t)(nb + row) * C_ + k0 + c4 * 8], &Bs[i2 * 8]);
        }
        __syncthreads();

        half8 af[4];
#pragma unroll
        for (int m = 0; m < 4; ++m)
            af[m] = *reinterpret_cast<const half8*>(&As[(wr * 64 + m * 16 + l15) * 32 + g * 8]);
#pragma unroll
        for (int n = 0; n < 4; ++n) {
            half8 bf = *reinterpret_cast<const half8*>(&Bs[(wc * 64 + n * 16 + l15) * 32 + g * 8]);
#pragma unroll
            for (int m = 0; m < 4; ++m)
                acc[m][n] = __builtin_amdgcn_mfma_f32_16x16x32_f16(af[m], bf, acc[m][n], 0, 0, 0);
        }
    }

#pragma unroll
    for (int n = 0; n < 4; ++n) {
        int col = nb + wc * 64 + n * 16 + l15;
        float bb = bias[col];
#pragma unroll
        for (int m = 0; m < 4; ++m)
#pragma unroll
            for (int r = 0; r < 4; ++r) {
                size_t row = mb + wr * 64 + m * 16 + g * 4 + r;
                out[row * C_ + col] = acc[m][n][r] + bb;
            }
    }
}

extern "C" void kernel_launch(void* const* d_in, const int* in_sizes, int n_in,
                              void* d_out, int out_size, void* d_ws, size_t ws_size,
                              hipStream_t stream)
{
    const float* x    = (const float*)d_in[0];
    const int*   mask = (const int*)  d_in[1];
    const float* Wq   = (const float*)d_in[2];
    const float* bq   = (const float*)d_in[3];
    const float* Wk   = (const float*)d_in[4];
    const float* bk   = (const float*)d_in[5];
    const float* Wv   = (const float*)d_in[6];
    const float* bv   = (const float*)d_in[7];
    const float* Wo   = (const float*)d_in[8];
    const float* bo   = (const float*)d_in[9];
    const float* rel  = (const float*)d_in[10];
    float* out = (float*)d_out;

    const size_t XN = (size_t)B_ * S_ * C_;   // 4,194,304
    const size_t WN = (size_t)C_ * C_;        // 1,048,576

    f16* wsh  = (f16*)d_ws;
    f16* xh   = wsh;                  // 4M
    f16* Wqh  = wsh + XN;             // 4 x 1M (Wq,Wk,Wv,Wo contiguous)
    f16* Woh  = Wqh + 3 * WN;
    f16* qh   = wsh + XN + 4 * WN;    // 4M
    f16* kh   = qh + XN;
    f16* vh   = kh + XN;
    f16* ctxh = vh + XN;              // total 24M halves = 48 MB

    convert_inputs<<<8192, 256, 0, stream>>>(x, Wq, Wk, Wv, Wo, wsh);
    qkv_gemm_h<<<dim3(32, 8, 3), 256, 0, stream>>>(xh, Wqh, bq, bk, bv, qh, kh, vh);
    attn_mfma<<<dim3(32, 32), 256, 0, stream>>>(qh, kh, vh, mask, rel, ctxh);
    out_gemm_h<<<dim3(32, 8), 256, 0, stream>>>(ctxh, Woh, bo, out);
}